// Round 1
// baseline (369.145 us; speedup 1.0000x reference)
//
#include <hip/hip_runtime.h>
#include <math.h>

#define HH 960
#define WW 1280
#define NPIX (HH*WW)
#define NBLK (NPIX/256)   // 4800
#define BPR (WW/256)      // 5 blocks per image row

// workspace layout (bytes)
#define WS_POSE_OFF    0          // 16 floats
#define WS_MINMAX_OFF  64         // 2 uints
#define WS_PARTIAL_OFF 256        // NBLK*27 floats = 518400 B
#define WS_V1N1_OFF    519168     // NPIX*6 floats = 29491200 B
#define WS_GXGY_OFF    30010368   // NPIX*6 floats -> total 59501568 B (~57 MiB)

__device__ __forceinline__ int clampi(int v, int lo, int hi){ return v<lo?lo:(v>hi?hi:v); }

// ---------------- init: copy pose, init min/max slots ----------------
__global__ void k_init(const float* __restrict__ pose_in, float* __restrict__ pose,
                       unsigned* __restrict__ minmax){
  int t = threadIdx.x;
  if (t < 16) pose[t] = pose_in[t];
  if (t == 0){ minmax[0] = 0x7F800000u; /* +inf */ minmax[1] = 0u; /* +0.0 */ }
}

// ---------------- global min/max of depth1 (positive floats -> uint monotonic) ----------------
__global__ __launch_bounds__(256) void k_minmax(const float* __restrict__ depth1,
                                                unsigned* __restrict__ minmax){
  float mn = INFINITY, mx = 0.f;
  for (int i = blockIdx.x*blockDim.x + threadIdx.x; i < NPIX; i += gridDim.x*blockDim.x){
    float d = depth1[i];
    mn = fminf(mn, d); mx = fmaxf(mx, d);
  }
  #pragma unroll
  for (int off = 32; off; off >>= 1){
    mn = fminf(mn, __shfl_down(mn, off));
    mx = fmaxf(mx, __shfl_down(mx, off));
  }
  if ((threadIdx.x & 63) == 0){
    atomicMin(&minmax[0], __float_as_uint(mn));
    atomicMax(&minmax[1], __float_as_uint(mx));
  }
}

// ---------------- vertex1 + normal1, interleaved 6 floats/pixel ----------------
__global__ __launch_bounds__(256) void k_v1n1(const float* __restrict__ depth1,
                                              const float* __restrict__ Kd,
                                              const unsigned* __restrict__ minmax,
                                              float* __restrict__ v1n1){
  int bid = blockIdx.x;
  int py = bid / BPR;
  int px = (bid % BPR)*256 + threadIdx.x;
  float fx = Kd[0], fy = Kd[4], cx = Kd[2], cy = Kd[5];
  float vx[3][3], vy[3][3], vz[3][3];
  #pragma unroll
  for (int dr = 0; dr < 3; dr++){
    int r = clampi(py + dr - 1, 0, HH-1);
    #pragma unroll
    for (int dc = 0; dc < 3; dc++){
      int c = clampi(px + dc - 1, 0, WW-1);
      float d = depth1[r*WW + c];
      vx[dr][dc] = ((float)c - cx)/fx*d;
      vy[dr][dc] = ((float)r - cy)/fy*d;
      vz[dr][dc] = d;
    }
  }
  // sobel (unnormalized): dx = d/dcol, dy = d/drow
  float ax_ = (vx[0][2]-vx[0][0]) + 2.f*(vx[1][2]-vx[1][0]) + (vx[2][2]-vx[2][0]);
  float ay_ = (vy[0][2]-vy[0][0]) + 2.f*(vy[1][2]-vy[1][0]) + (vy[2][2]-vy[2][0]);
  float az_ = (vz[0][2]-vz[0][0]) + 2.f*(vz[1][2]-vz[1][0]) + (vz[2][2]-vz[2][0]);
  float bx_ = (vx[2][0]-vx[0][0]) + 2.f*(vx[2][1]-vx[0][1]) + (vx[2][2]-vx[0][2]);
  float by_ = (vy[2][0]-vy[0][0]) + 2.f*(vy[2][1]-vy[0][1]) + (vy[2][2]-vy[0][2]);
  float bz_ = (vz[2][0]-vz[0][0]) + 2.f*(vz[2][1]-vz[0][1]) + (vz[2][2]-vz[0][2]);
  float nx = ay_*bz_ - az_*by_;
  float ny = az_*bx_ - ax_*bz_;
  float nz = ax_*by_ - ay_*bx_;
  float nrm = sqrtf(nx*nx + ny*ny + nz*nz) + 1e-8f;
  nx /= nrm; ny /= nrm; nz /= nrm;
  float dcen = vz[1][1];
  float dmn = __uint_as_float(minmax[0]);
  float dmx = __uint_as_float(minmax[1]);
  if (dcen <= dmn || dcen >= dmx){ nx = 0.f; ny = 0.f; nz = 0.f; }
  int idx = py*WW + px;
  float* o = &v1n1[idx*6];
  o[0] = vx[1][1]; o[1] = vy[1][1]; o[2] = vz[1][1];
  o[3] = nx; o[4] = ny; o[5] = nz;
}

// ---------------- normalized sobel of x0: gx[3], gy[3] per pixel ----------------
__global__ __launch_bounds__(256) void k_gxgy(const float* __restrict__ x0,
                                              float* __restrict__ gxgy){
  int bid = blockIdx.x;
  int py = bid / BPR;
  int px = (bid % BPR)*256 + threadIdx.x;
  float p[3][3][3];
  #pragma unroll
  for (int dr = 0; dr < 3; dr++){
    int r = clampi(py + dr - 1, 0, HH-1);
    #pragma unroll
    for (int dc = 0; dc < 3; dc++){
      int c = clampi(px + dc - 1, 0, WW-1);
      const float* q = &x0[(r*WW + c)*3];
      p[dr][dc][0] = q[0]; p[dr][dc][1] = q[1]; p[dr][dc][2] = q[2];
    }
  }
  int idx = py*WW + px;
  #pragma unroll
  for (int ch = 0; ch < 3; ch++){
    float dx = (p[0][2][ch]-p[0][0][ch]) + 2.f*(p[1][2][ch]-p[1][0][ch]) + (p[2][2][ch]-p[2][0][ch]);
    float dy = (p[2][0][ch]-p[0][0][ch]) + 2.f*(p[2][1][ch]-p[0][1][ch]) + (p[2][2][ch]-p[0][2][ch]);
    float mag = sqrtf(dx*dx + dy*dy + 1e-8f);
    gxgy[idx*6 + ch]     = dx/mag;
    gxgy[idx*6 + 3 + ch] = dy/mag;
  }
}

// ---------------- fused per-pixel ICP + RGB normal-equation accumulation ----------------
__global__ __launch_bounds__(256) void k_main(const float* __restrict__ depth0,
                                              const float* __restrict__ x0,
                                              const float* __restrict__ x1,
                                              const float* __restrict__ Kd,
                                              const float* __restrict__ pose,
                                              const float* __restrict__ v1n1,
                                              const float* __restrict__ gxgy,
                                              float* __restrict__ partial){
  int bid = blockIdx.x;
  int py = bid / BPR;
  int px = (bid % BPR)*256 + threadIdx.x;
  int idx = py*WW + px;
  float fx = Kd[0], fy = Kd[4], cx = Kd[2], cy = Kd[5];
  float R00=pose[0], R01=pose[1], R02=pose[2],  tx=pose[3];
  float R10=pose[4], R11=pose[5], R12=pose[6],  ty=pose[7];
  float R20=pose[8], R21=pose[9], R22=pose[10], tz=pose[11];

  float d0 = depth0[idx];
  bool m0 = d0 > 0.f;
  float v0x = ((float)px - cx)/fx*d0;
  float v0y = ((float)py - cy)/fy*d0;
  float v0z = d0;
  float X = R00*v0x + R01*v0y + R02*v0z + tx;
  float Y = R10*v0x + R11*v0y + R12*v0z + ty;
  float Z = R20*v0x + R21*v0y + R22*v0z + tz;
  float u = X/Z*fx + cx;
  float v = Y/Z*fy + cy;
  bool inview = (u > 0.f) && (u < (float)(WW-1)) && (v > 0.f) && (v < (float)(HH-1)) && (Z > 0.f);

  float uc = fminf(fmaxf(u, 0.f), (float)(WW-1));
  float vc = fminf(fmaxf(v, 0.f), (float)(HH-1));
  float u0f = floorf(uc), v0f = floorf(vc);
  float wu = uc - u0f, wv = vc - v0f;
  int u0i = clampi((int)u0f, 0, WW-1);
  int v0i = clampi((int)v0f, 0, HH-1);
  int u1i = min(u0i + 1, WW-1);
  int v1i = min(v0i + 1, HH-1);
  int i00 = v0i*WW + u0i, i01 = v0i*WW + u1i, i10 = v1i*WW + u0i, i11 = v1i*WW + u1i;
  float w00 = (1.f-wu)*(1.f-wv), w01 = wu*(1.f-wv), w10 = (1.f-wu)*wv, w11 = wu*wv;

  const float* t00 = &v1n1[i00*6];
  const float* t01 = &v1n1[i01*6];
  const float* t10 = &v1n1[i10*6];
  const float* t11 = &v1n1[i11*6];
  float s[6];
  #pragma unroll
  for (int k = 0; k < 6; k++)
    s[k] = t00[k]*w00 + t01[k]*w01 + t10[k]*w10 + t11[k]*w11;

  float dfx = X - s[0], dfy = Y - s[1], dfz = Z - s[2];
  float nx = s[3], ny = s[4], nz = s[5];
  bool valid = inview && m0 && (s[2] > 0.f) && (dfx*dfx + dfy*dfy + dfz*dfz < 0.01f);
  float res = 0.f;
  float J[6] = {0.f,0.f,0.f,0.f,0.f,0.f};
  if (valid){
    res = nx*dfx + ny*dfy + nz*dfz;
    J[0] = Y*nz - Z*ny;
    J[1] = Z*nx - X*nz;
    J[2] = X*ny - Y*nx;
    J[3] = nx; J[4] = ny; J[5] = nz;
  }
  float axv = fabsf(res);
  float rho = (axv <= 0.02f) ? axv*axv : (0.04f*axv - 0.0004f);
  float xs  = (axv < 1e-8f) ? 1.f : axv;
  float hw  = sqrtf(rho + 1e-16f)/xs;
  float wr  = hw*res;
  float wJ[6];
  #pragma unroll
  for (int i = 0; i < 6; i++) wJ[i] = hw*J[i];

  float acc[27];
  {
    int k = 0;
    #pragma unroll
    for (int i = 0; i < 6; i++)
      #pragma unroll
      for (int j = i; j < 6; j++)
        acc[k++] = wJ[i]*wJ[j];
  }
  #pragma unroll
  for (int i = 0; i < 6; i++) acc[21+i] = wJ[i]*wr;

  if (inview && m0){
    const float* c00 = &x1[i00*3];
    const float* c01 = &x1[i01*3];
    const float* c10 = &x1[i10*3];
    const float* c11 = &x1[i11*3];
    const float* xc  = &x0[idx*3];
    float rr[3];
    #pragma unroll
    for (int ch = 0; ch < 3; ch++){
      float xw = c00[ch]*w00 + c01[ch]*w01 + c10[ch]*w10 + c11[ch]*w11;
      rr[ch] = xw - xc[ch];
    }
    float invD = 1.f/d0, invD2 = invD*invD;
    float xy = v0x*v0y;
    float Jx[6] = { fx*(-invD2*xy), fx*(1.f + v0x*v0x*invD2), fx*(-v0y*invD), fx*invD, 0.f, fx*(-invD2*v0x) };
    float Jy[6] = { fy*(-1.f - invD2*v0y*v0y), fy*(xy*invD2), fy*(v0x*invD), 0.f, fy*invD, fy*(-invD2*v0y) };
    const float* g = &gxgy[idx*6];
    #pragma unroll
    for (int ch = 0; ch < 3; ch++){
      float gx = g[ch], gy = g[3+ch];
      float Jc[6];
      #pragma unroll
      for (int i = 0; i < 6; i++) Jc[i] = gx*Jx[i] + gy*Jy[i];
      int k = 0;
      #pragma unroll
      for (int i = 0; i < 6; i++)
        #pragma unroll
        for (int j = i; j < 6; j++)
          acc[k++] += 1e-6f*(Jc[i]*Jc[j]);
      #pragma unroll
      for (int i = 0; i < 6; i++) acc[21+i] += 1e-6f*Jc[i]*rr[ch];
    }
  }

  // block reduction: wave shfl -> LDS -> 27 floats per block
  __shared__ float lds[108];
  int lane = threadIdx.x & 63;
  int wid  = threadIdx.x >> 6;
  #pragma unroll
  for (int k = 0; k < 27; k++){
    float vv = acc[k];
    vv += __shfl_down(vv, 32); vv += __shfl_down(vv, 16); vv += __shfl_down(vv, 8);
    vv += __shfl_down(vv, 4);  vv += __shfl_down(vv, 2);  vv += __shfl_down(vv, 1);
    if (lane == 0) lds[wid*27 + k] = vv;
  }
  __syncthreads();
  if (threadIdx.x < 27)
    partial[bid*27 + threadIdx.x] =
      lds[threadIdx.x] + lds[27+threadIdx.x] + lds[54+threadIdx.x] + lds[81+threadIdx.x];
}

// ---------------- final reduce + damped 6x6 solve + pose update (double) ----------------
__global__ __launch_bounds__(256) void k_solve(const float* __restrict__ partial,
                                               float* __restrict__ pose,
                                               float* __restrict__ outp){
  double acc[27];
  #pragma unroll
  for (int k = 0; k < 27; k++) acc[k] = 0.0;
  for (int r = threadIdx.x; r < NBLK; r += 256){
    const float* p = &partial[r*27];
    #pragma unroll
    for (int k = 0; k < 27; k++) acc[k] += (double)p[k];
  }
  __shared__ double lds[108];
  int lane = threadIdx.x & 63;
  int wid  = threadIdx.x >> 6;
  #pragma unroll
  for (int k = 0; k < 27; k++){
    double vv = acc[k];
    vv += __shfl_down(vv, 32); vv += __shfl_down(vv, 16); vv += __shfl_down(vv, 8);
    vv += __shfl_down(vv, 4);  vv += __shfl_down(vv, 2);  vv += __shfl_down(vv, 1);
    if (lane == 0) lds[wid*27 + k] = vv;
  }
  __syncthreads();
  if (threadIdx.x == 0){
    double s[27];
    #pragma unroll
    for (int k = 0; k < 27; k++) s[k] = lds[k] + lds[27+k] + lds[54+k] + lds[81+k];
    double Hm[6][6], b[6];
    {
      int k = 0;
      for (int i = 0; i < 6; i++)
        for (int j = i; j < 6; j++){ Hm[i][j] = s[k]; Hm[j][i] = s[k]; k++; }
      for (int i = 0; i < 6; i++) b[i] = s[21+i];
    }
    double tr = Hm[0][0]+Hm[1][1]+Hm[2][2]+Hm[3][3]+Hm[4][4]+Hm[5][5];
    for (int i = 0; i < 6; i++) Hm[i][i] += tr*0.001;
    // Gauss-Jordan with partial pivoting
    double A[6][7];
    for (int i = 0; i < 6; i++){
      for (int j = 0; j < 6; j++) A[i][j] = Hm[i][j];
      A[i][6] = b[i];
    }
    for (int c = 0; c < 6; c++){
      int piv = c; double best = fabs(A[c][c]);
      for (int r = c+1; r < 6; r++){ double a = fabs(A[r][c]); if (a > best){ best = a; piv = r; } }
      if (piv != c)
        for (int j = 0; j < 7; j++){ double t = A[c][j]; A[c][j] = A[piv][j]; A[piv][j] = t; }
      double inv = 1.0/A[c][c];
      for (int r = 0; r < 6; r++){
        if (r == c) continue;
        double f = A[r][c]*inv;
        for (int j = c; j < 7; j++) A[r][j] -= f*A[c][j];
      }
    }
    double xi[6];
    for (int i = 0; i < 6; i++) xi[i] = A[i][6]/A[i][i];
    // dR = exp_so3(-xi[:3])
    double wx = -xi[0], wy = -xi[1], wz = -xi[2];
    double th2 = wx*wx + wy*wy + wz*wz;
    if (th2 < 1e-30) th2 = 1e-30;
    double th = sqrt(th2);
    double dR[3][3];
    if (th <= 1e-10){
      dR[0][0]=1; dR[0][1]=0; dR[0][2]=0;
      dR[1][0]=0; dR[1][1]=1; dR[1][2]=0;
      dR[2][0]=0; dR[2][1]=0; dR[2][2]=1;
    } else {
      double sa = sin(th)/th;
      double sb = (1.0 - cos(th))/th2;
      double Wm[3][3] = {{0,-wz,wy},{wz,0,-wx},{-wy,wx,0}};
      double W2[3][3];
      for (int i = 0; i < 3; i++)
        for (int j = 0; j < 3; j++)
          W2[i][j] = Wm[i][0]*Wm[0][j] + Wm[i][1]*Wm[1][j] + Wm[i][2]*Wm[2][j];
      for (int i = 0; i < 3; i++)
        for (int j = 0; j < 3; j++)
          dR[i][j] = (i==j ? 1.0 : 0.0) + sa*Wm[i][j] + sb*W2[i][j];
    }
    double dt[3];
    for (int i = 0; i < 3; i++)
      dt[i] = -(dR[i][0]*xi[3] + dR[i][1]*xi[4] + dR[i][2]*xi[5]);
    double Ro[3][3], to[3];
    for (int i = 0; i < 3; i++){
      for (int j = 0; j < 3; j++) Ro[i][j] = (double)pose[i*4+j];
      to[i] = (double)pose[i*4+3];
    }
    double Rn[3][3], tn[3];
    for (int i = 0; i < 3; i++){
      for (int j = 0; j < 3; j++)
        Rn[i][j] = dR[i][0]*Ro[0][j] + dR[i][1]*Ro[1][j] + dR[i][2]*Ro[2][j];
      tn[i] = dR[i][0]*to[0] + dR[i][1]*to[1] + dR[i][2]*to[2] + dt[i];
    }
    float o16[16];
    for (int i = 0; i < 3; i++){
      for (int j = 0; j < 3; j++) o16[i*4+j] = (float)Rn[i][j];
      o16[i*4+3] = (float)tn[i];
    }
    o16[12] = 0.f; o16[13] = 0.f; o16[14] = 0.f; o16[15] = 1.f;
    for (int k = 0; k < 16; k++){ pose[k] = o16[k]; outp[k] = o16[k]; }
  }
}

extern "C" void kernel_launch(void* const* d_in, const int* in_sizes, int n_in,
                              void* d_out, int out_size, void* d_ws, size_t ws_size,
                              hipStream_t stream) {
  const float* pose10 = (const float*)d_in[0];
  const float* depth0 = (const float*)d_in[1];
  const float* depth1 = (const float*)d_in[2];
  const float* x0     = (const float*)d_in[3];
  const float* x1     = (const float*)d_in[4];
  const float* Kd     = (const float*)d_in[5];
  char* ws = (char*)d_ws;
  float*    pose    = (float*)(ws + WS_POSE_OFF);
  unsigned* minmax  = (unsigned*)(ws + WS_MINMAX_OFF);
  float*    partial = (float*)(ws + WS_PARTIAL_OFF);
  float*    v1n1    = (float*)(ws + WS_V1N1_OFF);
  float*    gxgy    = (float*)(ws + WS_GXGY_OFF);
  float*    outp    = (float*)d_out;

  hipLaunchKernelGGL(k_init,   dim3(1),    dim3(64),  0, stream, pose10, pose, minmax);
  hipLaunchKernelGGL(k_minmax, dim3(600),  dim3(256), 0, stream, depth1, minmax);
  hipLaunchKernelGGL(k_v1n1,   dim3(NBLK), dim3(256), 0, stream, depth1, Kd, minmax, v1n1);
  hipLaunchKernelGGL(k_gxgy,   dim3(NBLK), dim3(256), 0, stream, x0, gxgy);
  for (int it = 0; it < 3; it++){
    hipLaunchKernelGGL(k_main,  dim3(NBLK), dim3(256), 0, stream,
                       depth0, x0, x1, Kd, pose, v1n1, gxgy, partial);
    hipLaunchKernelGGL(k_solve, dim3(1),    dim3(256), 0, stream, partial, pose, outp);
  }
}

// Round 2
// 333.658 us; speedup vs baseline: 1.1064x; 1.1064x over previous
//
#include <hip/hip_runtime.h>
#include <math.h>

#define HH 960
#define WW 1280
#define NPIX (HH*WW)
#define NBLK_ROW (NPIX/256)  // 4800, row-mapped blocks for k_n1
#define BPR (WW/256)         // 5 blocks per image row
#define PPT 2
#define NBLK_MAIN (NPIX/(256*PPT))  // 2400

// workspace layout (bytes)
#define WS_POSE_OFF    0          // 16 floats
#define WS_MINMAX_OFF  64         // 2 uints
#define WS_PARTIAL_OFF 256        // NBLK_MAIN*27 floats = 259200 B
#define WS_N1_OFF      262144     // NPIX*3 floats = 14745600 B  (total ~15 MiB)

__device__ __forceinline__ int clampi(int v, int lo, int hi){ return v<lo?lo:(v>hi?hi:v); }

// ---------------- init: copy pose, init min/max slots ----------------
__global__ void k_init(const float* __restrict__ pose_in, float* __restrict__ pose,
                       unsigned* __restrict__ minmax){
  int t = threadIdx.x;
  if (t < 16) pose[t] = pose_in[t];
  if (t == 0){ minmax[0] = 0x7F800000u; minmax[1] = 0u; }
}

// ---------------- global min/max of depth1 (positive floats -> uint monotonic) ----------------
__global__ __launch_bounds__(256) void k_minmax(const float* __restrict__ depth1,
                                                unsigned* __restrict__ minmax){
  float mn = INFINITY, mx = 0.f;
  for (int i = blockIdx.x*blockDim.x + threadIdx.x; i < NPIX; i += gridDim.x*blockDim.x){
    float d = depth1[i];
    mn = fminf(mn, d); mx = fmaxf(mx, d);
  }
  #pragma unroll
  for (int off = 32; off; off >>= 1){
    mn = fminf(mn, __shfl_down(mn, off));
    mx = fmaxf(mx, __shfl_down(mx, off));
  }
  if ((threadIdx.x & 63) == 0){
    atomicMin(&minmax[0], __float_as_uint(mn));
    atomicMax(&minmax[1], __float_as_uint(mx));
  }
}

// ---------------- normal1 only (12 B/pixel); vertex recomputed later from depth1 ----------------
__global__ __launch_bounds__(256) void k_n1(const float* __restrict__ depth1,
                                            const float* __restrict__ Kd,
                                            const unsigned* __restrict__ minmax,
                                            float* __restrict__ n1){
  int bid = blockIdx.x;
  int py = bid / BPR;
  int px = (bid % BPR)*256 + threadIdx.x;
  float fx = Kd[0], fy = Kd[4], cx = Kd[2], cy = Kd[5];
  float vx[3][3], vy[3][3], vz[3][3];
  #pragma unroll
  for (int dr = 0; dr < 3; dr++){
    int r = clampi(py + dr - 1, 0, HH-1);
    #pragma unroll
    for (int dc = 0; dc < 3; dc++){
      int c = clampi(px + dc - 1, 0, WW-1);
      float d = depth1[r*WW + c];
      vx[dr][dc] = ((float)c - cx)/fx*d;
      vy[dr][dc] = ((float)r - cy)/fy*d;
      vz[dr][dc] = d;
    }
  }
  float ax_ = (vx[0][2]-vx[0][0]) + 2.f*(vx[1][2]-vx[1][0]) + (vx[2][2]-vx[2][0]);
  float ay_ = (vy[0][2]-vy[0][0]) + 2.f*(vy[1][2]-vy[1][0]) + (vy[2][2]-vy[2][0]);
  float az_ = (vz[0][2]-vz[0][0]) + 2.f*(vz[1][2]-vz[1][0]) + (vz[2][2]-vz[2][0]);
  float bx_ = (vx[2][0]-vx[0][0]) + 2.f*(vx[2][1]-vx[0][1]) + (vx[2][2]-vx[0][2]);
  float by_ = (vy[2][0]-vy[0][0]) + 2.f*(vy[2][1]-vy[0][1]) + (vy[2][2]-vy[0][2]);
  float bz_ = (vz[2][0]-vz[0][0]) + 2.f*(vz[2][1]-vz[0][1]) + (vz[2][2]-vz[0][2]);
  float nx = ay_*bz_ - az_*by_;
  float ny = az_*bx_ - ax_*bz_;
  float nz = ax_*by_ - ay_*bx_;
  float nrm = sqrtf(nx*nx + ny*ny + nz*nz) + 1e-8f;
  nx /= nrm; ny /= nrm; nz /= nrm;
  float dcen = vz[1][1];
  float dmn = __uint_as_float(minmax[0]);
  float dmx = __uint_as_float(minmax[1]);
  if (dcen <= dmn || dcen >= dmx){ nx = 0.f; ny = 0.f; nz = 0.f; }
  int idx = py*WW + px;
  n1[idx*3+0] = nx; n1[idx*3+1] = ny; n1[idx*3+2] = nz;
}

// ---------------- fused per-pixel ICP + RGB normal-equation accumulation ----------------
__global__ __launch_bounds__(256) void k_main(const float* __restrict__ depth0,
                                              const float* __restrict__ x0,
                                              const float* __restrict__ x1,
                                              const float* __restrict__ depth1,
                                              const float* __restrict__ Kd,
                                              const float* __restrict__ pose,
                                              const float* __restrict__ n1,
                                              float* __restrict__ partial){
  int t = threadIdx.x;
  int base = blockIdx.x*(256*PPT) + t;
  float fx = Kd[0], fy = Kd[4], cx = Kd[2], cy = Kd[5];
  float inv_fx = 1.f/fx, inv_fy = 1.f/fy;
  float R00=pose[0], R01=pose[1], R02=pose[2],  tx=pose[3];
  float R10=pose[4], R11=pose[5], R12=pose[6],  ty=pose[7];
  float R20=pose[8], R21=pose[9], R22=pose[10], tz=pose[11];

  float acc[27];
  #pragma unroll
  for (int k = 0; k < 27; k++) acc[k] = 0.f;

  #pragma unroll
  for (int kp = 0; kp < PPT; kp++){
    int idx = base + kp*256;
    int py = idx / WW;
    int px = idx - py*WW;

    float d0 = depth0[idx];
    bool m0 = d0 > 0.f;
    float v0x = ((float)px - cx)*inv_fx*d0;
    float v0y = ((float)py - cy)*inv_fy*d0;
    float v0z = d0;
    float X = R00*v0x + R01*v0y + R02*v0z + tx;
    float Y = R10*v0x + R11*v0y + R12*v0z + ty;
    float Z = R20*v0x + R21*v0y + R22*v0z + tz;
    float invZ = 1.f/Z;
    float u = X*invZ*fx + cx;
    float v = Y*invZ*fy + cy;
    bool inview = (u > 0.f) && (u < (float)(WW-1)) && (v > 0.f) && (v < (float)(HH-1)) && (Z > 0.f);

    float uc = fminf(fmaxf(u, 0.f), (float)(WW-1));
    float vc = fminf(fmaxf(v, 0.f), (float)(HH-1));
    float u0f = floorf(uc), v0f = floorf(vc);
    float wu = uc - u0f, wv = vc - v0f;
    int u0i = clampi((int)u0f, 0, WW-1);
    int v0i = clampi((int)v0f, 0, HH-1);
    int u1i = min(u0i + 1, WW-1);
    int v1i = min(v0i + 1, HH-1);
    int i00 = v0i*WW + u0i, i01 = v0i*WW + u1i, i10 = v1i*WW + u0i, i11 = v1i*WW + u1i;
    float w00 = (1.f-wu)*(1.f-wv), w01 = wu*(1.f-wv), w10 = (1.f-wu)*wv, w11 = wu*wv;

    // vertex1 taps recomputed exactly from depth1 (same math as compute_vertex)
    float d00 = depth1[i00], d01 = depth1[i01], d10 = depth1[i10], d11 = depth1[i11];
    float u0c = ((float)u0i - cx)*inv_fx, u1c = ((float)u1i - cx)*inv_fx;
    float v0c = ((float)v0i - cy)*inv_fy, v1c = ((float)v1i - cy)*inv_fy;
    float s0 = w00*(u0c*d00) + w01*(u1c*d01) + w10*(u0c*d10) + w11*(u1c*d11);
    float s1 = w00*(v0c*d00) + w01*(v0c*d01) + w10*(v1c*d10) + w11*(v1c*d11);
    float s2 = w00*d00 + w01*d01 + w10*d10 + w11*d11;
    // normal1 taps
    const float* t00 = &n1[i00*3];
    const float* t01 = &n1[i01*3];
    const float* t10 = &n1[i10*3];
    const float* t11 = &n1[i11*3];
    float nx = t00[0]*w00 + t01[0]*w01 + t10[0]*w10 + t11[0]*w11;
    float ny = t00[1]*w00 + t01[1]*w01 + t10[1]*w10 + t11[1]*w11;
    float nz = t00[2]*w00 + t01[2]*w01 + t10[2]*w10 + t11[2]*w11;

    float dfx = X - s0, dfy = Y - s1, dfz = Z - s2;
    bool valid = inview && m0 && (s2 > 0.f) && (dfx*dfx + dfy*dfy + dfz*dfz < 0.01f);
    float res = 0.f;
    float J[6] = {0.f,0.f,0.f,0.f,0.f,0.f};
    if (valid){
      res = nx*dfx + ny*dfy + nz*dfz;
      J[0] = Y*nz - Z*ny;
      J[1] = Z*nx - X*nz;
      J[2] = X*ny - Y*nx;
      J[3] = nx; J[4] = ny; J[5] = nz;
    }
    float axv = fabsf(res);
    float rho = (axv <= 0.02f) ? axv*axv : (0.04f*axv - 0.0004f);
    float xs  = (axv < 1e-8f) ? 1.f : axv;
    float hw  = sqrtf(rho + 1e-16f)/xs;
    float wr  = hw*res;
    float wJ[6];
    #pragma unroll
    for (int i = 0; i < 6; i++) wJ[i] = hw*J[i];
    {
      int k = 0;
      #pragma unroll
      for (int i = 0; i < 6; i++)
        #pragma unroll
        for (int j = i; j < 6; j++)
          acc[k++] += wJ[i]*wJ[j];
      #pragma unroll
      for (int i = 0; i < 6; i++) acc[21+i] += wJ[i]*wr;
    }

    if (inview && m0){
      // x0 3x3 neighborhood (clamped) for sobel + center for rgb residual
      int r0 = clampi(py-1, 0, HH-1), r2 = clampi(py+1, 0, HH-1);
      int c0 = clampi(px-1, 0, WW-1), c2 = clampi(px+1, 0, WW-1);
      float p[3][3][3];
      const int rows[3] = {r0, py, r2};
      const int cols[3] = {c0, px, c2};
      #pragma unroll
      for (int dr = 0; dr < 3; dr++)
        #pragma unroll
        for (int dc = 0; dc < 3; dc++){
          const float* q = &x0[(rows[dr]*WW + cols[dc])*3];
          p[dr][dc][0] = q[0]; p[dr][dc][1] = q[1]; p[dr][dc][2] = q[2];
        }
      // x1 bilinear taps
      const float* c00 = &x1[i00*3];
      const float* c01 = &x1[i01*3];
      const float* c10 = &x1[i10*3];
      const float* c11 = &x1[i11*3];

      float invD = 1.f/d0, invD2 = invD*invD;
      float xy = v0x*v0y;
      float Jx[6] = { fx*(-invD2*xy), fx*(1.f + v0x*v0x*invD2), fx*(-v0y*invD), fx*invD, 0.f, fx*(-invD2*v0x) };
      float Jy[6] = { fy*(-1.f - invD2*v0y*v0y), fy*(xy*invD2), fy*(v0x*invD), 0.f, fy*invD, fy*(-invD2*v0y) };

      #pragma unroll
      for (int ch = 0; ch < 3; ch++){
        float dx = (p[0][2][ch]-p[0][0][ch]) + 2.f*(p[1][2][ch]-p[1][0][ch]) + (p[2][2][ch]-p[2][0][ch]);
        float dy = (p[2][0][ch]-p[0][0][ch]) + 2.f*(p[2][1][ch]-p[0][1][ch]) + (p[2][2][ch]-p[0][2][ch]);
        float mag = sqrtf(dx*dx + dy*dy + 1e-8f);
        float gx = dx/mag, gy = dy/mag;
        float xw = c00[ch]*w00 + c01[ch]*w01 + c10[ch]*w10 + c11[ch]*w11;
        float rr = xw - p[1][1][ch];
        float Jc[6];
        #pragma unroll
        for (int i = 0; i < 6; i++) Jc[i] = gx*Jx[i] + gy*Jy[i];
        int k = 0;
        #pragma unroll
        for (int i = 0; i < 6; i++)
          #pragma unroll
          for (int j = i; j < 6; j++)
            acc[k++] += 1e-6f*(Jc[i]*Jc[j]);
        #pragma unroll
        for (int i = 0; i < 6; i++) acc[21+i] += 1e-6f*Jc[i]*rr;
      }
    }
  }

  // block reduction: wave shfl -> LDS -> 27 floats per block
  __shared__ float lds[108];
  int lane = t & 63;
  int wid  = t >> 6;
  #pragma unroll
  for (int k = 0; k < 27; k++){
    float vv = acc[k];
    vv += __shfl_down(vv, 32); vv += __shfl_down(vv, 16); vv += __shfl_down(vv, 8);
    vv += __shfl_down(vv, 4);  vv += __shfl_down(vv, 2);  vv += __shfl_down(vv, 1);
    if (lane == 0) lds[wid*27 + k] = vv;
  }
  __syncthreads();
  if (t < 27)
    partial[blockIdx.x*27 + t] =
      lds[t] + lds[27+t] + lds[54+t] + lds[81+t];
}

// ---------------- final reduce + damped 6x6 solve + pose update (double) ----------------
__global__ __launch_bounds__(256) void k_solve(const float* __restrict__ partial,
                                               float* __restrict__ pose,
                                               float* __restrict__ outp){
  double acc[27];
  #pragma unroll
  for (int k = 0; k < 27; k++) acc[k] = 0.0;
  for (int r = threadIdx.x; r < NBLK_MAIN; r += 256){
    const float* p = &partial[r*27];
    #pragma unroll
    for (int k = 0; k < 27; k++) acc[k] += (double)p[k];
  }
  __shared__ double lds[108];
  int lane = threadIdx.x & 63;
  int wid  = threadIdx.x >> 6;
  #pragma unroll
  for (int k = 0; k < 27; k++){
    double vv = acc[k];
    vv += __shfl_down(vv, 32); vv += __shfl_down(vv, 16); vv += __shfl_down(vv, 8);
    vv += __shfl_down(vv, 4);  vv += __shfl_down(vv, 2);  vv += __shfl_down(vv, 1);
    if (lane == 0) lds[wid*27 + k] = vv;
  }
  __syncthreads();
  if (threadIdx.x == 0){
    double s[27];
    #pragma unroll
    for (int k = 0; k < 27; k++) s[k] = lds[k] + lds[27+k] + lds[54+k] + lds[81+k];
    double Hm[6][6], b[6];
    {
      int k = 0;
      for (int i = 0; i < 6; i++)
        for (int j = i; j < 6; j++){ Hm[i][j] = s[k]; Hm[j][i] = s[k]; k++; }
      for (int i = 0; i < 6; i++) b[i] = s[21+i];
    }
    double tr = Hm[0][0]+Hm[1][1]+Hm[2][2]+Hm[3][3]+Hm[4][4]+Hm[5][5];
    for (int i = 0; i < 6; i++) Hm[i][i] += tr*0.001;
    double A[6][7];
    for (int i = 0; i < 6; i++){
      for (int j = 0; j < 6; j++) A[i][j] = Hm[i][j];
      A[i][6] = b[i];
    }
    for (int c = 0; c < 6; c++){
      int piv = c; double best = fabs(A[c][c]);
      for (int r = c+1; r < 6; r++){ double a = fabs(A[r][c]); if (a > best){ best = a; piv = r; } }
      if (piv != c)
        for (int j = 0; j < 7; j++){ double tv = A[c][j]; A[c][j] = A[piv][j]; A[piv][j] = tv; }
      double inv = 1.0/A[c][c];
      for (int r = 0; r < 6; r++){
        if (r == c) continue;
        double f = A[r][c]*inv;
        for (int j = c; j < 7; j++) A[r][j] -= f*A[c][j];
      }
    }
    double xi[6];
    for (int i = 0; i < 6; i++) xi[i] = A[i][6]/A[i][i];
    double wx = -xi[0], wy = -xi[1], wz = -xi[2];
    double th2 = wx*wx + wy*wy + wz*wz;
    if (th2 < 1e-30) th2 = 1e-30;
    double th = sqrt(th2);
    double dR[3][3];
    if (th <= 1e-10){
      dR[0][0]=1; dR[0][1]=0; dR[0][2]=0;
      dR[1][0]=0; dR[1][1]=1; dR[1][2]=0;
      dR[2][0]=0; dR[2][1]=0; dR[2][2]=1;
    } else {
      double sa = sin(th)/th;
      double sb = (1.0 - cos(th))/th2;
      double Wm[3][3] = {{0,-wz,wy},{wz,0,-wx},{-wy,wx,0}};
      double W2[3][3];
      for (int i = 0; i < 3; i++)
        for (int j = 0; j < 3; j++)
          W2[i][j] = Wm[i][0]*Wm[0][j] + Wm[i][1]*Wm[1][j] + Wm[i][2]*Wm[2][j];
      for (int i = 0; i < 3; i++)
        for (int j = 0; j < 3; j++)
          dR[i][j] = (i==j ? 1.0 : 0.0) + sa*Wm[i][j] + sb*W2[i][j];
    }
    double dt[3];
    for (int i = 0; i < 3; i++)
      dt[i] = -(dR[i][0]*xi[3] + dR[i][1]*xi[4] + dR[i][2]*xi[5]);
    double Ro[3][3], to[3];
    for (int i = 0; i < 3; i++){
      for (int j = 0; j < 3; j++) Ro[i][j] = (double)pose[i*4+j];
      to[i] = (double)pose[i*4+3];
    }
    double Rn[3][3], tn[3];
    for (int i = 0; i < 3; i++){
      for (int j = 0; j < 3; j++)
        Rn[i][j] = dR[i][0]*Ro[0][j] + dR[i][1]*Ro[1][j] + dR[i][2]*Ro[2][j];
      tn[i] = dR[i][0]*to[0] + dR[i][1]*to[1] + dR[i][2]*to[2] + dt[i];
    }
    float o16[16];
    for (int i = 0; i < 3; i++){
      for (int j = 0; j < 3; j++) o16[i*4+j] = (float)Rn[i][j];
      o16[i*4+3] = (float)tn[i];
    }
    o16[12] = 0.f; o16[13] = 0.f; o16[14] = 0.f; o16[15] = 1.f;
    for (int k = 0; k < 16; k++){ pose[k] = o16[k]; outp[k] = o16[k]; }
  }
}

extern "C" void kernel_launch(void* const* d_in, const int* in_sizes, int n_in,
                              void* d_out, int out_size, void* d_ws, size_t ws_size,
                              hipStream_t stream) {
  const float* pose10 = (const float*)d_in[0];
  const float* depth0 = (const float*)d_in[1];
  const float* depth1 = (const float*)d_in[2];
  const float* x0     = (const float*)d_in[3];
  const float* x1     = (const float*)d_in[4];
  const float* Kd     = (const float*)d_in[5];
  char* ws = (char*)d_ws;
  float*    pose    = (float*)(ws + WS_POSE_OFF);
  unsigned* minmax  = (unsigned*)(ws + WS_MINMAX_OFF);
  float*    partial = (float*)(ws + WS_PARTIAL_OFF);
  float*    n1      = (float*)(ws + WS_N1_OFF);
  float*    outp    = (float*)d_out;

  hipLaunchKernelGGL(k_init,   dim3(1),        dim3(64),  0, stream, pose10, pose, minmax);
  hipLaunchKernelGGL(k_minmax, dim3(600),      dim3(256), 0, stream, depth1, minmax);
  hipLaunchKernelGGL(k_n1,     dim3(NBLK_ROW), dim3(256), 0, stream, depth1, Kd, minmax, n1);
  for (int it = 0; it < 3; it++){
    hipLaunchKernelGGL(k_main,  dim3(NBLK_MAIN), dim3(256), 0, stream,
                       depth0, x0, x1, depth1, Kd, pose, n1, partial);
    hipLaunchKernelGGL(k_solve, dim3(1),         dim3(256), 0, stream, partial, pose, outp);
  }
}

// Round 3
// 281.925 us; speedup vs baseline: 1.3094x; 1.1835x over previous
//
#include <hip/hip_runtime.h>
#include <math.h>

#define HH 960
#define WW 1280
#define NPIX (HH*WW)
#define NBLK_ROW (NPIX/256)      // 4800 row-mapped blocks for k_n1
#define BPR (WW/256)             // 5 col-segments per image row
#define NBLK_MAIN (NPIX/(256*2)) // 2400: 2-row x 256-col tiles
#define MM_BLOCKS 512
#define TW 258                   // x0 tile width (256 + 2 halo)

// workspace layout (bytes)
#define WS_POSE_OFF    0          // 16 floats
#define WS_MINMAX_OFF  64         // 2 floats
#define WS_BMIN_OFF    128        // 512 floats
#define WS_BMAX_OFF    2176       // 512 floats
#define WS_PARTIAL_OFF 4352       // 2400*27 floats = 259200 B
#define WS_N1P_OFF     263680     // NPIX float4 = 19660800 B
#define WS_X1P_OFF     19924480   // NPIX float4 -> total 39585280 B (~38 MiB)

__device__ __forceinline__ int clampi(int v, int lo, int hi){ return v<lo?lo:(v>hi?hi:v); }

// ---------------- stage1: block min/max of depth1 (no atomics) + pack x1->float4 + pose copy ----------------
__global__ __launch_bounds__(256) void k_mm1(const float* __restrict__ depth1,
                                             const float* __restrict__ x1,
                                             const float* __restrict__ pose_in,
                                             float* __restrict__ pose,
                                             float* __restrict__ x1p,
                                             float* __restrict__ bmin,
                                             float* __restrict__ bmax){
  int t = threadIdx.x;
  if (blockIdx.x == 0 && t < 16) pose[t] = pose_in[t];
  float mn = INFINITY, mx = 0.f;
  for (int i = blockIdx.x*256 + t; i < NPIX; i += MM_BLOCKS*256){
    float d = depth1[i];
    mn = fminf(mn, d); mx = fmaxf(mx, d);
    const float* q = &x1[i*3];
    float4 o; o.x = q[0]; o.y = q[1]; o.z = q[2]; o.w = 0.f;
    ((float4*)x1p)[i] = o;
  }
  #pragma unroll
  for (int off = 32; off; off >>= 1){
    mn = fminf(mn, __shfl_down(mn, off));
    mx = fmaxf(mx, __shfl_down(mx, off));
  }
  __shared__ float smn[4], smx[4];
  int lane = t & 63, wid = t >> 6;
  if (lane == 0){ smn[wid] = mn; smx[wid] = mx; }
  __syncthreads();
  if (t == 0){
    bmin[blockIdx.x] = fminf(fminf(smn[0], smn[1]), fminf(smn[2], smn[3]));
    bmax[blockIdx.x] = fmaxf(fmaxf(smx[0], smx[1]), fmaxf(smx[2], smx[3]));
  }
}

// ---------------- stage2: reduce 512 partials -> minmax[2] ----------------
__global__ __launch_bounds__(256) void k_mm2(const float* __restrict__ bmin,
                                             const float* __restrict__ bmax,
                                             float* __restrict__ minmax){
  int t = threadIdx.x;
  float mn = fminf(bmin[t], bmin[t+256]);
  float mx = fmaxf(bmax[t], bmax[t+256]);
  #pragma unroll
  for (int off = 32; off; off >>= 1){
    mn = fminf(mn, __shfl_down(mn, off));
    mx = fmaxf(mx, __shfl_down(mx, off));
  }
  __shared__ float smn[4], smx[4];
  int lane = t & 63, wid = t >> 6;
  if (lane == 0){ smn[wid] = mn; smx[wid] = mx; }
  __syncthreads();
  if (t == 0){
    minmax[0] = fminf(fminf(smn[0], smn[1]), fminf(smn[2], smn[3]));
    minmax[1] = fmaxf(fmaxf(smx[0], smx[1]), fmaxf(smx[2], smx[3]));
  }
}

// ---------------- normal1 as float4 (16 B/pixel) ----------------
__global__ __launch_bounds__(256) void k_n1(const float* __restrict__ depth1,
                                            const float* __restrict__ Kd,
                                            const float* __restrict__ minmax,
                                            float* __restrict__ n1p){
  int bid = blockIdx.x;
  int py = bid / BPR;
  int px = (bid % BPR)*256 + threadIdx.x;
  float fx = Kd[0], fy = Kd[4], cx = Kd[2], cy = Kd[5];
  float vx[3][3], vy[3][3], vz[3][3];
  #pragma unroll
  for (int dr = 0; dr < 3; dr++){
    int r = clampi(py + dr - 1, 0, HH-1);
    #pragma unroll
    for (int dc = 0; dc < 3; dc++){
      int c = clampi(px + dc - 1, 0, WW-1);
      float d = depth1[r*WW + c];
      vx[dr][dc] = ((float)c - cx)/fx*d;
      vy[dr][dc] = ((float)r - cy)/fy*d;
      vz[dr][dc] = d;
    }
  }
  float ax_ = (vx[0][2]-vx[0][0]) + 2.f*(vx[1][2]-vx[1][0]) + (vx[2][2]-vx[2][0]);
  float ay_ = (vy[0][2]-vy[0][0]) + 2.f*(vy[1][2]-vy[1][0]) + (vy[2][2]-vy[2][0]);
  float az_ = (vz[0][2]-vz[0][0]) + 2.f*(vz[1][2]-vz[1][0]) + (vz[2][2]-vz[2][0]);
  float bx_ = (vx[2][0]-vx[0][0]) + 2.f*(vx[2][1]-vx[0][1]) + (vx[2][2]-vx[0][2]);
  float by_ = (vy[2][0]-vy[0][0]) + 2.f*(vy[2][1]-vy[0][1]) + (vy[2][2]-vy[0][2]);
  float bz_ = (vz[2][0]-vz[0][0]) + 2.f*(vz[2][1]-vz[0][1]) + (vz[2][2]-vz[0][2]);
  float nx = ay_*bz_ - az_*by_;
  float ny = az_*bx_ - ax_*bz_;
  float nz = ax_*by_ - ay_*bx_;
  float nrm = sqrtf(nx*nx + ny*ny + nz*nz) + 1e-8f;
  nx /= nrm; ny /= nrm; nz /= nrm;
  float dcen = vz[1][1];
  float dmn = minmax[0], dmx = minmax[1];
  if (dcen <= dmn || dcen >= dmx){ nx = 0.f; ny = 0.f; nz = 0.f; }
  float4 o; o.x = nx; o.y = ny; o.z = nz; o.w = 0.f;
  ((float4*)n1p)[py*WW + px] = o;
}

// ---------------- fused per-pixel ICP + RGB accumulation (2-row tile, LDS x0) ----------------
__global__ __launch_bounds__(256) void k_main(const float* __restrict__ depth0,
                                              const float* __restrict__ x0,
                                              const float* __restrict__ x1p,
                                              const float* __restrict__ depth1,
                                              const float* __restrict__ Kd,
                                              const float* __restrict__ pose,
                                              const float* __restrict__ n1p,
                                              float* __restrict__ partial){
  int t = threadIdx.x;
  int pr = blockIdx.x / BPR;        // row-pair index 0..479
  int cs = blockIdx.x % BPR;        // col segment
  int py0 = pr*2;
  int colbase = cs*256 - 1;
  int px = cs*256 + t;

  // cooperative x0 tile: rows py0-1..py0+2 (clamped), cols colbase..colbase+257 (clamped)
  __shared__ float tile[4*TW*3];    // 12384 B
  for (int s = t; s < 4*TW; s += 256){
    int r = s / TW, c = s - r*TW;
    int gr = clampi(py0 - 1 + r, 0, HH-1);
    int gc = clampi(colbase + c, 0, WW-1);
    const float* q = &x0[(gr*WW + gc)*3];
    tile[s*3+0] = q[0]; tile[s*3+1] = q[1]; tile[s*3+2] = q[2];
  }
  __syncthreads();

  float fx = Kd[0], fy = Kd[4], cx = Kd[2], cy = Kd[5];
  float inv_fx = 1.f/fx, inv_fy = 1.f/fy;
  float R00=pose[0], R01=pose[1], R02=pose[2],  tx=pose[3];
  float R10=pose[4], R11=pose[5], R12=pose[6],  ty=pose[7];
  float R20=pose[8], R21=pose[9], R22=pose[10], tz=pose[11];

  float acc[27];
  #pragma unroll
  for (int k = 0; k < 27; k++) acc[k] = 0.f;

  const float4* n1p4 = (const float4*)n1p;
  const float4* x1p4 = (const float4*)x1p;

  #pragma unroll
  for (int kp = 0; kp < 2; kp++){
    int py = py0 + kp;
    int idx = py*WW + px;

    float d0 = depth0[idx];
    bool m0 = d0 > 0.f;
    float v0x = ((float)px - cx)*inv_fx*d0;
    float v0y = ((float)py - cy)*inv_fy*d0;
    float v0z = d0;
    float X = R00*v0x + R01*v0y + R02*v0z + tx;
    float Y = R10*v0x + R11*v0y + R12*v0z + ty;
    float Z = R20*v0x + R21*v0y + R22*v0z + tz;
    float invZ = 1.f/Z;
    float u = X*invZ*fx + cx;
    float v = Y*invZ*fy + cy;
    bool inview = (u > 0.f) && (u < (float)(WW-1)) && (v > 0.f) && (v < (float)(HH-1)) && (Z > 0.f);

    float uc = fminf(fmaxf(u, 0.f), (float)(WW-1));
    float vc = fminf(fmaxf(v, 0.f), (float)(HH-1));
    float u0f = floorf(uc), v0f = floorf(vc);
    float wu = uc - u0f, wv = vc - v0f;
    int u0i = clampi((int)u0f, 0, WW-1);
    int v0i = clampi((int)v0f, 0, HH-1);
    int u1i = min(u0i + 1, WW-1);
    int v1i = min(v0i + 1, HH-1);
    int i00 = v0i*WW + u0i, i01 = v0i*WW + u1i, i10 = v1i*WW + u0i, i11 = v1i*WW + u1i;
    float w00 = (1.f-wu)*(1.f-wv), w01 = wu*(1.f-wv), w10 = (1.f-wu)*wv, w11 = wu*wv;

    // vertex1 taps recomputed from depth1 (exact compute_vertex math)
    float d00 = depth1[i00], d01 = depth1[i01], d10 = depth1[i10], d11 = depth1[i11];
    float u0c = ((float)u0i - cx)*inv_fx, u1c = ((float)u1i - cx)*inv_fx;
    float v0c = ((float)v0i - cy)*inv_fy, v1c = ((float)v1i - cy)*inv_fy;
    float s0 = w00*(u0c*d00) + w01*(u1c*d01) + w10*(u0c*d10) + w11*(u1c*d11);
    float s1 = w00*(v0c*d00) + w01*(v0c*d01) + w10*(v1c*d10) + w11*(v1c*d11);
    float s2 = w00*d00 + w01*d01 + w10*d10 + w11*d11;
    // normal1 taps (float4)
    float4 n00 = n1p4[i00], n01 = n1p4[i01], n10 = n1p4[i10], n11 = n1p4[i11];
    float nx = n00.x*w00 + n01.x*w01 + n10.x*w10 + n11.x*w11;
    float ny = n00.y*w00 + n01.y*w01 + n10.y*w10 + n11.y*w11;
    float nz = n00.z*w00 + n01.z*w01 + n10.z*w10 + n11.z*w11;

    float dfx = X - s0, dfy = Y - s1, dfz = Z - s2;
    bool valid = inview && m0 && (s2 > 0.f) && (dfx*dfx + dfy*dfy + dfz*dfz < 0.01f);
    float res = 0.f;
    float J[6] = {0.f,0.f,0.f,0.f,0.f,0.f};
    if (valid){
      res = nx*dfx + ny*dfy + nz*dfz;
      J[0] = Y*nz - Z*ny;
      J[1] = Z*nx - X*nz;
      J[2] = X*ny - Y*nx;
      J[3] = nx; J[4] = ny; J[5] = nz;
    }
    float axv = fabsf(res);
    float rho = (axv <= 0.02f) ? axv*axv : (0.04f*axv - 0.0004f);
    float xs  = (axv < 1e-8f) ? 1.f : axv;
    float hw  = sqrtf(rho + 1e-16f)/xs;
    float wr  = hw*res;
    float wJ[6];
    #pragma unroll
    for (int i = 0; i < 6; i++) wJ[i] = hw*J[i];
    {
      int k = 0;
      #pragma unroll
      for (int i = 0; i < 6; i++)
        #pragma unroll
        for (int j = i; j < 6; j++)
          acc[k++] += wJ[i]*wJ[j];
      #pragma unroll
      for (int i = 0; i < 6; i++) acc[21+i] += wJ[i]*wr;
    }

    if (inview && m0){
      float4 c00 = x1p4[i00], c01 = x1p4[i01], c10 = x1p4[i10], c11 = x1p4[i11];
      float xw0 = c00.x*w00 + c01.x*w01 + c10.x*w10 + c11.x*w11;
      float xw1 = c00.y*w00 + c01.y*w01 + c10.y*w10 + c11.y*w11;
      float xw2 = c00.z*w00 + c01.z*w01 + c10.z*w10 + c11.z*w11;

      float invD = 1.f/d0, invD2 = invD*invD;
      float xy = v0x*v0y;
      float Jx[6] = { fx*(-invD2*xy), fx*(1.f + v0x*v0x*invD2), fx*(-v0y*invD), fx*invD, 0.f, fx*(-invD2*v0x) };
      float Jy[6] = { fy*(-1.f - invD2*v0y*v0y), fy*(xy*invD2), fy*(v0x*invD), 0.f, fy*invD, fy*(-invD2*v0y) };

      float xw[3] = {xw0, xw1, xw2};
      #pragma unroll
      for (int ch = 0; ch < 3; ch++){
        // sobel from LDS tile: rows kp..kp+2, cols t..t+2
        float p00 = tile[((kp+0)*TW + (t+0))*3 + ch];
        float p01 = tile[((kp+0)*TW + (t+1))*3 + ch];
        float p02 = tile[((kp+0)*TW + (t+2))*3 + ch];
        float p10 = tile[((kp+1)*TW + (t+0))*3 + ch];
        float p11 = tile[((kp+1)*TW + (t+1))*3 + ch];
        float p12 = tile[((kp+1)*TW + (t+2))*3 + ch];
        float p20 = tile[((kp+2)*TW + (t+0))*3 + ch];
        float p21 = tile[((kp+2)*TW + (t+1))*3 + ch];
        float p22 = tile[((kp+2)*TW + (t+2))*3 + ch];
        float dx = (p02-p00) + 2.f*(p12-p10) + (p22-p20);
        float dy = (p20-p00) + 2.f*(p21-p01) + (p22-p02);
        float mag = sqrtf(dx*dx + dy*dy + 1e-8f);
        float gx = dx/mag, gy = dy/mag;
        float rr = xw[ch] - p11;
        float Jc[6];
        #pragma unroll
        for (int i = 0; i < 6; i++) Jc[i] = gx*Jx[i] + gy*Jy[i];
        int k = 0;
        #pragma unroll
        for (int i = 0; i < 6; i++)
          #pragma unroll
          for (int j = i; j < 6; j++)
            acc[k++] += 1e-6f*(Jc[i]*Jc[j]);
        #pragma unroll
        for (int i = 0; i < 6; i++) acc[21+i] += 1e-6f*Jc[i]*rr;
      }
    }
  }

  // block reduction: wave shfl -> LDS -> 27 floats per block
  __shared__ float lds[108];
  int lane = t & 63;
  int wid  = t >> 6;
  #pragma unroll
  for (int k = 0; k < 27; k++){
    float vv = acc[k];
    vv += __shfl_down(vv, 32); vv += __shfl_down(vv, 16); vv += __shfl_down(vv, 8);
    vv += __shfl_down(vv, 4);  vv += __shfl_down(vv, 2);  vv += __shfl_down(vv, 1);
    if (lane == 0) lds[wid*27 + k] = vv;
  }
  __syncthreads();
  if (t < 27)
    partial[blockIdx.x*27 + t] = lds[t] + lds[27+t] + lds[54+t] + lds[81+t];
}

// ---------------- final reduce + damped 6x6 solve + pose update (double) ----------------
__global__ __launch_bounds__(256) void k_solve(const float* __restrict__ partial,
                                               float* __restrict__ pose,
                                               float* __restrict__ outp){
  double acc[27];
  #pragma unroll
  for (int k = 0; k < 27; k++) acc[k] = 0.0;
  for (int r = threadIdx.x; r < NBLK_MAIN; r += 256){
    const float* p = &partial[r*27];
    #pragma unroll
    for (int k = 0; k < 27; k++) acc[k] += (double)p[k];
  }
  __shared__ double lds[108];
  int lane = threadIdx.x & 63;
  int wid  = threadIdx.x >> 6;
  #pragma unroll
  for (int k = 0; k < 27; k++){
    double vv = acc[k];
    vv += __shfl_down(vv, 32); vv += __shfl_down(vv, 16); vv += __shfl_down(vv, 8);
    vv += __shfl_down(vv, 4);  vv += __shfl_down(vv, 2);  vv += __shfl_down(vv, 1);
    if (lane == 0) lds[wid*27 + k] = vv;
  }
  __syncthreads();
  if (threadIdx.x == 0){
    double s[27];
    #pragma unroll
    for (int k = 0; k < 27; k++) s[k] = lds[k] + lds[27+k] + lds[54+k] + lds[81+k];
    double Hm[6][6], b[6];
    {
      int k = 0;
      for (int i = 0; i < 6; i++)
        for (int j = i; j < 6; j++){ Hm[i][j] = s[k]; Hm[j][i] = s[k]; k++; }
      for (int i = 0; i < 6; i++) b[i] = s[21+i];
    }
    double tr = Hm[0][0]+Hm[1][1]+Hm[2][2]+Hm[3][3]+Hm[4][4]+Hm[5][5];
    for (int i = 0; i < 6; i++) Hm[i][i] += tr*0.001;
    double A[6][7];
    for (int i = 0; i < 6; i++){
      for (int j = 0; j < 6; j++) A[i][j] = Hm[i][j];
      A[i][6] = b[i];
    }
    for (int c = 0; c < 6; c++){
      int piv = c; double best = fabs(A[c][c]);
      for (int r = c+1; r < 6; r++){ double a = fabs(A[r][c]); if (a > best){ best = a; piv = r; } }
      if (piv != c)
        for (int j = 0; j < 7; j++){ double tv = A[c][j]; A[c][j] = A[piv][j]; A[piv][j] = tv; }
      double inv = 1.0/A[c][c];
      for (int r = 0; r < 6; r++){
        if (r == c) continue;
        double f = A[r][c]*inv;
        for (int j = c; j < 7; j++) A[r][j] -= f*A[c][j];
      }
    }
    double xi[6];
    for (int i = 0; i < 6; i++) xi[i] = A[i][6]/A[i][i];
    double wx = -xi[0], wy = -xi[1], wz = -xi[2];
    double th2 = wx*wx + wy*wy + wz*wz;
    if (th2 < 1e-30) th2 = 1e-30;
    double th = sqrt(th2);
    double dR[3][3];
    if (th <= 1e-10){
      dR[0][0]=1; dR[0][1]=0; dR[0][2]=0;
      dR[1][0]=0; dR[1][1]=1; dR[1][2]=0;
      dR[2][0]=0; dR[2][1]=0; dR[2][2]=1;
    } else {
      double sa = sin(th)/th;
      double sb = (1.0 - cos(th))/th2;
      double Wm[3][3] = {{0,-wz,wy},{wz,0,-wx},{-wy,wx,0}};
      double W2[3][3];
      for (int i = 0; i < 3; i++)
        for (int j = 0; j < 3; j++)
          W2[i][j] = Wm[i][0]*Wm[0][j] + Wm[i][1]*Wm[1][j] + Wm[i][2]*Wm[2][j];
      for (int i = 0; i < 3; i++)
        for (int j = 0; j < 3; j++)
          dR[i][j] = (i==j ? 1.0 : 0.0) + sa*Wm[i][j] + sb*W2[i][j];
    }
    double dt[3];
    for (int i = 0; i < 3; i++)
      dt[i] = -(dR[i][0]*xi[3] + dR[i][1]*xi[4] + dR[i][2]*xi[5]);
    double Ro[3][3], to[3];
    for (int i = 0; i < 3; i++){
      for (int j = 0; j < 3; j++) Ro[i][j] = (double)pose[i*4+j];
      to[i] = (double)pose[i*4+3];
    }
    double Rn[3][3], tn[3];
    for (int i = 0; i < 3; i++){
      for (int j = 0; j < 3; j++)
        Rn[i][j] = dR[i][0]*Ro[0][j] + dR[i][1]*Ro[1][j] + dR[i][2]*Ro[2][j];
      tn[i] = dR[i][0]*to[0] + dR[i][1]*to[1] + dR[i][2]*to[2] + dt[i];
    }
    float o16[16];
    for (int i = 0; i < 3; i++){
      for (int j = 0; j < 3; j++) o16[i*4+j] = (float)Rn[i][j];
      o16[i*4+3] = (float)tn[i];
    }
    o16[12] = 0.f; o16[13] = 0.f; o16[14] = 0.f; o16[15] = 1.f;
    for (int k = 0; k < 16; k++){ pose[k] = o16[k]; outp[k] = o16[k]; }
  }
}

extern "C" void kernel_launch(void* const* d_in, const int* in_sizes, int n_in,
                              void* d_out, int out_size, void* d_ws, size_t ws_size,
                              hipStream_t stream) {
  const float* pose10 = (const float*)d_in[0];
  const float* depth0 = (const float*)d_in[1];
  const float* depth1 = (const float*)d_in[2];
  const float* x0     = (const float*)d_in[3];
  const float* x1     = (const float*)d_in[4];
  const float* Kd     = (const float*)d_in[5];
  char* ws = (char*)d_ws;
  float* pose    = (float*)(ws + WS_POSE_OFF);
  float* minmax  = (float*)(ws + WS_MINMAX_OFF);
  float* bmin    = (float*)(ws + WS_BMIN_OFF);
  float* bmax    = (float*)(ws + WS_BMAX_OFF);
  float* partial = (float*)(ws + WS_PARTIAL_OFF);
  float* n1p     = (float*)(ws + WS_N1P_OFF);
  float* x1p     = (float*)(ws + WS_X1P_OFF);
  float* outp    = (float*)d_out;

  hipLaunchKernelGGL(k_mm1, dim3(MM_BLOCKS), dim3(256), 0, stream,
                     depth1, x1, pose10, pose, x1p, bmin, bmax);
  hipLaunchKernelGGL(k_mm2, dim3(1),         dim3(256), 0, stream, bmin, bmax, minmax);
  hipLaunchKernelGGL(k_n1,  dim3(NBLK_ROW),  dim3(256), 0, stream, depth1, Kd, minmax, n1p);
  for (int it = 0; it < 3; it++){
    hipLaunchKernelGGL(k_main,  dim3(NBLK_MAIN), dim3(256), 0, stream,
                       depth0, x0, x1p, depth1, Kd, pose, n1p, partial);
    hipLaunchKernelGGL(k_solve, dim3(1),         dim3(256), 0, stream, partial, pose, outp);
  }
}